// Round 1
// baseline (646.020 us; speedup 1.0000x reference)
//
#include <hip/hip_runtime.h>

// PositionAwareAttention: S=8192, B=64, D=512, A=256, all fp32 I/O.
// Strategy: fused flash-style. x read from HBM exactly once (1.07 GB).
//   k0: Wx fp32 -> fp16 (ws)
//   k1: whb[b,a] = h[b,:]. Wh[a,:] + bx[a] (ws)
//   k2: per (b, 64-row s-tile): GEMM wx = x.W^T via f16 MFMA (x staged to a
//       persistent padded fp16 LDS tile, K pipelined in 8 chunks of 64, W
//       double-buffered), epilogue tanh+Wt reduce -> tile-local softmax
//       partial (m, l, acc[512]) to ws.
//   k3: combine partials over the 128 tiles of each b -> out[b,d].
// bt is omitted: softmax is shift-invariant.

#define S_DIM 8192
#define B_DIM 64
#define D_DIM 512
#define A_DIM 256
#define BM 64
#define BK 64
#define NCHUNK 8              // D / BK
#define XS_LD 520             // fp16 elems per xs row (512 + 8 pad: kills bank conflicts on a-frag reads)
#define WS_LD 72              // fp16 elems per W row (64 + 8 pad)
#define NTILES 128            // S / BM

typedef _Float16 half8 __attribute__((ext_vector_type(8)));
typedef float f32x4 __attribute__((ext_vector_type(4)));

// LDS: xs[64][520] f16 (66560 B) + W dbuf 2*[256][72] f16 (73728 B) + smalls
#define SMEM_MAIN (BM*XS_LD*2 + 2*A_DIM*WS_LD*2 + (4*BM + BM + A_DIM + A_DIM)*4)

__device__ __forceinline__ float tanh_fast(float x) {
  // tanh(x) = 1 - 2/(exp(2x)+1); exp->inf/0 saturates correctly to +/-1
  float e = __expf(2.0f * x);
  return 1.0f - 2.0f * __builtin_amdgcn_rcpf(e + 1.0f);
}

__global__ void __launch_bounds__(256)
convw_kernel(const float* __restrict__ Wx, _Float16* __restrict__ Wf) {
  const int idx = (blockIdx.x * 256 + threadIdx.x) * 8;
  f32x4 a = *(const f32x4*)(Wx + idx);
  f32x4 b = *(const f32x4*)(Wx + idx + 4);
  half8 hx;
#pragma unroll
  for (int i = 0; i < 4; ++i) { hx[i] = (_Float16)a[i]; hx[4 + i] = (_Float16)b[i]; }
  *(half8*)(Wf + idx) = hx;
}

__global__ void __launch_bounds__(256)
whb_kernel(const float* __restrict__ h, const float* __restrict__ Wh,
           const float* __restrict__ bx, float* __restrict__ whb) {
  __shared__ float hs[D_DIM];
  const int b = blockIdx.x, tid = threadIdx.x;
  hs[tid] = h[b * D_DIM + tid];
  hs[tid + 256] = h[b * D_DIM + 256 + tid];
  __syncthreads();
  const int g = tid >> 4, i = tid & 15;  // 16 lanes cooperate on one a-row
  for (int pass = 0; pass < 16; ++pass) {
    const int a = pass * 16 + g;
    const f32x4* wrow = (const f32x4*)(Wh + (size_t)a * D_DIM);
    float dot = 0.f;
#pragma unroll
    for (int k = 0; k < 8; ++k) {
      f32x4 wv = wrow[i + k * 16];
      f32x4 hv = *(const f32x4*)(hs + (i + k * 16) * 4);
      dot += wv[0] * hv[0] + wv[1] * hv[1] + wv[2] * hv[2] + wv[3] * hv[3];
    }
#pragma unroll
    for (int mask = 1; mask < 16; mask <<= 1) dot += __shfl_xor(dot, mask, 64);
    if (i == 0) whb[b * A_DIM + a] = dot + bx[a];
  }
}

__global__ void __launch_bounds__(512, 2)
paa_main(const float* __restrict__ x, const _Float16* __restrict__ Wf,
         const float* __restrict__ whb, const float* __restrict__ Wt,
         float* __restrict__ m_arr, float* __restrict__ l_arr,
         float* __restrict__ acc_arr) {
  extern __shared__ char smem[];
  _Float16* xs = (_Float16*)smem;                                   // [BM][XS_LD]
  _Float16* wsm = (_Float16*)(smem + BM * XS_LD * 2);               // [2][A][WS_LD]
  float* scorep = (float*)(smem + BM * XS_LD * 2 + 2 * A_DIM * WS_LD * 2);  // [4][BM]
  float* pbuf = scorep + 4 * BM;                                    // [BM]
  float* whb_s = pbuf + BM;                                         // [A]
  float* wt_s = whb_s + A_DIM;                                      // [A]

  const int tid = threadIdx.x;
  const int b = blockIdx.y;
  const int tile = blockIdx.x;
  const int s0 = tile * BM;

  if (tid < A_DIM) { whb_s[tid] = whb[b * A_DIM + tid]; wt_s[tid] = Wt[tid]; }

  // staging maps
  const int xr = tid >> 3, xj = tid & 7;   // x: row r=tid/8, 8-float segment j
  const float* xg = x + (size_t)(s0 + xr) * (B_DIM * D_DIM) + b * D_DIM + xj * 8;
  const int wa = tid >> 1, wh2 = tid & 1;  // W: row a=tid/2, 32-elem half
  const _Float16* wg = Wf + wa * D_DIM + wh2 * 32;

  f32x4 xre0, xre1;
  half8 wre0, wre1, wre2, wre3;

  auto load_chunk = [&](int c) {
    const float* p = xg + c * BK;
    xre0 = *(const f32x4*)(p);
    xre1 = *(const f32x4*)(p + 4);
    const _Float16* q = wg + c * BK;
    wre0 = *(const half8*)(q);
    wre1 = *(const half8*)(q + 8);
    wre2 = *(const half8*)(q + 16);
    wre3 = *(const half8*)(q + 24);
  };
  auto write_chunk = [&](int c) {
    half8 hx;
#pragma unroll
    for (int i = 0; i < 4; ++i) { hx[i] = (_Float16)xre0[i]; hx[4 + i] = (_Float16)xre1[i]; }
    *(half8*)(xs + xr * XS_LD + c * BK + xj * 8) = hx;
    _Float16* wb = wsm + (c & 1) * (A_DIM * WS_LD) + wa * WS_LD + wh2 * 32;
    *(half8*)(wb) = wre0;
    *(half8*)(wb + 8) = wre1;
    *(half8*)(wb + 16) = wre2;
    *(half8*)(wb + 24) = wre3;
  };

  f32x4 acc[2][4];
#pragma unroll
  for (int i = 0; i < 2; ++i)
#pragma unroll
    for (int j = 0; j < 4; ++j) acc[i][j] = (f32x4){0.f, 0.f, 0.f, 0.f};

  const int lane = tid & 63;
  const int wv = tid >> 6;
  const int wm = wv >> 2, wn = wv & 3;     // wave tile: rows wm*32+.., cols wn*64+..
  const int fr = lane & 15, fg = lane >> 4;
  const int a_row0 = wm * 32 + fr;
  const int b_row0 = wn * 64 + fr;

  load_chunk(0);
  write_chunk(0);
  __syncthreads();

  for (int c = 0; c < NCHUNK; ++c) {
    if (c + 1 < NCHUNK) load_chunk(c + 1);   // HBM/L2 loads in flight across MFMAs
    const _Float16* wbase = wsm + (c & 1) * (A_DIM * WS_LD);
#pragma unroll
    for (int kk = 0; kk < 2; ++kk) {
      half8 af0 = *(const half8*)(xs + (a_row0)*XS_LD + c * BK + kk * 32 + fg * 8);
      half8 af1 = *(const half8*)(xs + (a_row0 + 16) * XS_LD + c * BK + kk * 32 + fg * 8);
      half8 bf0 = *(const half8*)(wbase + (b_row0)*WS_LD + kk * 32 + fg * 8);
      half8 bf1 = *(const half8*)(wbase + (b_row0 + 16) * WS_LD + kk * 32 + fg * 8);
      half8 bf2 = *(const half8*)(wbase + (b_row0 + 32) * WS_LD + kk * 32 + fg * 8);
      half8 bf3 = *(const half8*)(wbase + (b_row0 + 48) * WS_LD + kk * 32 + fg * 8);
      acc[0][0] = __builtin_amdgcn_mfma_f32_16x16x32_f16(af0, bf0, acc[0][0], 0, 0, 0);
      acc[0][1] = __builtin_amdgcn_mfma_f32_16x16x32_f16(af0, bf1, acc[0][1], 0, 0, 0);
      acc[0][2] = __builtin_amdgcn_mfma_f32_16x16x32_f16(af0, bf2, acc[0][2], 0, 0, 0);
      acc[0][3] = __builtin_amdgcn_mfma_f32_16x16x32_f16(af0, bf3, acc[0][3], 0, 0, 0);
      acc[1][0] = __builtin_amdgcn_mfma_f32_16x16x32_f16(af1, bf0, acc[1][0], 0, 0, 0);
      acc[1][1] = __builtin_amdgcn_mfma_f32_16x16x32_f16(af1, bf1, acc[1][1], 0, 0, 0);
      acc[1][2] = __builtin_amdgcn_mfma_f32_16x16x32_f16(af1, bf2, acc[1][2], 0, 0, 0);
      acc[1][3] = __builtin_amdgcn_mfma_f32_16x16x32_f16(af1, bf3, acc[1][3], 0, 0, 0);
    }
    if (c + 1 < NCHUNK) write_chunk(c + 1);  // writes go to the other W buffer / fresh xs region
    __syncthreads();
  }

  // epilogue: score[s] = sum_a Wt[a] * tanh(wx + whb)  (C frag: row=fg*4+reg, col=fr)
  float part[2][4];
#pragma unroll
  for (int mi = 0; mi < 2; ++mi)
#pragma unroll
    for (int r = 0; r < 4; ++r) part[mi][r] = 0.f;
#pragma unroll
  for (int ni = 0; ni < 4; ++ni) {
    const int a_idx = wn * 64 + ni * 16 + fr;
    const float wt_a = wt_s[a_idx];
    const float whb_a = whb_s[a_idx];
#pragma unroll
    for (int mi = 0; mi < 2; ++mi)
#pragma unroll
      for (int r = 0; r < 4; ++r)
        part[mi][r] += wt_a * tanh_fast(acc[mi][ni][r] + whb_a);
  }
#pragma unroll
  for (int mask = 1; mask < 16; mask <<= 1) {
#pragma unroll
    for (int mi = 0; mi < 2; ++mi)
#pragma unroll
      for (int r = 0; r < 4; ++r) part[mi][r] += __shfl_xor(part[mi][r], mask, 64);
  }
  if (fr == 0) {
#pragma unroll
    for (int mi = 0; mi < 2; ++mi)
#pragma unroll
      for (int r = 0; r < 4; ++r)
        scorep[wn * BM + wm * 32 + mi * 16 + fg * 4 + r] = part[mi][r];
  }
  __syncthreads();

  // tile-local softmax partial
  if (tid < BM) {
    float sv = scorep[tid] + scorep[BM + tid] + scorep[2 * BM + tid] + scorep[3 * BM + tid];
    float m = sv;
#pragma unroll
    for (int mask = 1; mask < 64; mask <<= 1) m = fmaxf(m, __shfl_xor(m, mask, 64));
    float p = __expf(sv - m);
    float lsum = p;
#pragma unroll
    for (int mask = 1; mask < 64; mask <<= 1) lsum += __shfl_xor(lsum, mask, 64);
    pbuf[tid] = p;
    if (tid == 0) {
      m_arr[b * NTILES + tile] = m;
      l_arr[b * NTILES + tile] = lsum;
    }
  }
  __syncthreads();

  // acc[d] = sum_r p[r] * x[r][d], from the resident fp16 tile (vectorized per-wave rows)
  {
    float pacc[8];
#pragma unroll
    for (int j = 0; j < 8; ++j) pacc[j] = 0.f;
#pragma unroll
    for (int r = 0; r < 8; ++r) {
      const int row = wv * 8 + r;
      const float pr = pbuf[row];
      half8 v = *(const half8*)(xs + row * XS_LD + lane * 8);
#pragma unroll
      for (int j = 0; j < 8; ++j) pacc[j] += pr * (float)v[j];
    }
    float* red = (float*)wsm;  // reuse W buffers: 8*512*4 = 16 KB
#pragma unroll
    for (int j = 0; j < 8; ++j) red[wv * 512 + lane * 8 + j] = pacc[j];
    __syncthreads();
    float s = 0.f;
#pragma unroll
    for (int w2 = 0; w2 < 8; ++w2) s += red[w2 * 512 + tid];
    acc_arr[((size_t)(b * NTILES + tile)) * D_DIM + tid] = s;
  }
}

__global__ void __launch_bounds__(512)
combine_kernel(const float* __restrict__ m_arr, const float* __restrict__ l_arr,
               const float* __restrict__ acc_arr, float* __restrict__ out) {
  __shared__ float ml[NTILES], ls[NTILES], wl[NTILES];
  const int b = blockIdx.x, tid = threadIdx.x;
  if (tid < NTILES) {
    ml[tid] = m_arr[b * NTILES + tid];
    ls[tid] = l_arr[b * NTILES + tid];
  }
  __syncthreads();
  float M = -1e30f;
  for (int i = 0; i < NTILES; ++i) M = fmaxf(M, ml[i]);
  if (tid < NTILES) wl[tid] = __expf(ml[tid] - M);
  __syncthreads();
  float L = 0.f;
  for (int i = 0; i < NTILES; ++i) L += wl[i] * ls[i];
  float sum = 0.f;
  const size_t base = (size_t)b * NTILES * D_DIM + tid;
  for (int i = 0; i < NTILES; ++i) sum += wl[i] * acc_arr[base + (size_t)i * D_DIM];
  out[b * D_DIM + tid] = sum / L;
}

extern "C" void kernel_launch(void* const* d_in, const int* in_sizes, int n_in,
                              void* d_out, int out_size, void* d_ws, size_t ws_size,
                              hipStream_t stream) {
  const float* x = (const float*)d_in[0];
  const float* h = (const float*)d_in[1];
  const float* Wx = (const float*)d_in[2];
  const float* bx = (const float*)d_in[3];
  const float* Wh = (const float*)d_in[4];
  const float* Wt = (const float*)d_in[5];
  // d_in[6] = bt: unused (softmax shift-invariant)

  char* ws = (char*)d_ws;
  _Float16* Wf = (_Float16*)ws;                               // 262144 B
  float* whb = (float*)(ws + 262144);                         // 65536 B
  float* m_arr = (float*)(ws + 262144 + 65536);               // 32768 B
  float* l_arr = (float*)(ws + 262144 + 65536 + 32768);       // 32768 B
  float* acc_arr = (float*)(ws + 262144 + 65536 + 65536);     // 16.8 MB

  hipFuncSetAttribute(reinterpret_cast<const void*>(paa_main),
                      hipFuncAttributeMaxDynamicSharedMemorySize, SMEM_MAIN);

  hipLaunchKernelGGL(convw_kernel, dim3(64), dim3(256), 0, stream, Wx, Wf);
  hipLaunchKernelGGL(whb_kernel, dim3(B_DIM), dim3(256), 0, stream, h, Wh, bx, whb);
  hipLaunchKernelGGL(paa_main, dim3(NTILES, B_DIM), dim3(512), SMEM_MAIN, stream,
                     x, Wf, whb, Wt, m_arr, l_arr, acc_arr);
  hipLaunchKernelGGL(combine_kernel, dim3(B_DIM), dim3(512), 0, stream,
                     m_arr, l_arr, acc_arr, (float*)d_out);
}